// Round 4
// baseline (13347.272 us; speedup 1.0000x reference)
//
#include <hip/hip_runtime.h>
#include <hip/hip_fp16.h>
#include <math.h>

#define HD   512
#define BB   256
#define TT   200
#define DIN  64
#define DOUT 64
#define NCLS 10
#define LIPC 0.909f
#define NPAIR 128
#define XSLOT 640

// d_ws layout (bytes):
#define GS_BYTES   407552                       // gs: (TT-1)*HD floats
#define OFF_WX     0                            // fp16 pack offsets (halves)
#define OFF_WEMB   32768
#define OFF_WF1    557056
#define OFF_WF2    819200
#define OFF_WOUT   1081344
#define OFF_WDEC   1343488
#define NHALVES    1376256
#define XBUF_OFF   (GS_BYTES + NHALVES * 2)             // 3160064
#define XBUF_FLOATS (2 * NPAIR * 2 * XSLOT)             // parity x pair x half x slot
#define FLAG_OFF   (XBUF_OFF + XBUF_FLOATS * 4)         // 4470784
// total ws need ~= 4.47 MB

__device__ __forceinline__ float lipswish(float x) {
    return LIPC * x / (1.0f + expf(-x));
}

// ---------------------------------------------------------------------------
// fp32 -> fp16 weight conversion (unchanged from round 3)
// ---------------------------------------------------------------------------
__global__ __launch_bounds__(512) void cvt_kernel(
    const float* __restrict__ W_X,  const float* __restrict__ W_emb,
    const float* __restrict__ Wf1,  const float* __restrict__ Wf2,
    const float* __restrict__ W_out, const float* __restrict__ W_dec,
    __half* __restrict__ dst)
{
    int bid = blockIdx.x;
    size_t idx = ((size_t)bid << 9) + threadIdx.x;
    const float* src; size_t off;
    if      (bid < 64)   { src = W_X;   off = OFF_WX;   }
    else if (bid < 1088) { src = W_emb; off = OFF_WEMB; }
    else if (bid < 1600) { src = Wf1;   off = OFF_WF1;  }
    else if (bid < 2112) { src = Wf2;   off = OFF_WF2;  }
    else if (bid < 2624) { src = W_out; off = OFF_WOUT; }
    else                 { src = W_dec; off = OFF_WDEC; }
    dst[idx] = __float2half(src[idx - off]);
}

// ---------------------------------------------------------------------------
// fp32 full-width partial matvec (g_kernel only): 4 k-groups x 128 float4-cols
// ---------------------------------------------------------------------------
template<int K>
__device__ __forceinline__ void mv_part(const float* __restrict__ W,
                                        const float* src, float* part, int j)
{
    const int g = j >> 7, c = j & 127;
    const int kpg = K >> 2;
    const int k0 = g * kpg;
    const float4* __restrict__ W4 = (const float4*)W;
    float4 acc; acc.x = acc.y = acc.z = acc.w = 0.f;
#pragma unroll 2
    for (int k = k0; k < k0 + kpg; k += 4) {
        float4 a  = *(const float4*)(src + k);
        float4 w0 = W4[(size_t)(k + 0) * 128 + c];
        float4 w1 = W4[(size_t)(k + 1) * 128 + c];
        float4 w2 = W4[(size_t)(k + 2) * 128 + c];
        float4 w3 = W4[(size_t)(k + 3) * 128 + c];
        acc.x = fmaf(a.x, w0.x, acc.x); acc.y = fmaf(a.x, w0.y, acc.y);
        acc.z = fmaf(a.x, w0.z, acc.z); acc.w = fmaf(a.x, w0.w, acc.w);
        acc.x = fmaf(a.y, w1.x, acc.x); acc.y = fmaf(a.y, w1.y, acc.y);
        acc.z = fmaf(a.y, w1.z, acc.z); acc.w = fmaf(a.y, w1.w, acc.w);
        acc.x = fmaf(a.z, w2.x, acc.x); acc.y = fmaf(a.z, w2.y, acc.y);
        acc.z = fmaf(a.z, w2.z, acc.z); acc.w = fmaf(a.z, w2.w, acc.w);
        acc.x = fmaf(a.w, w3.x, acc.x); acc.y = fmaf(a.w, w3.y, acc.y);
        acc.z = fmaf(a.w, w3.z, acc.z); acc.w = fmaf(a.w, w3.w, acc.w);
    }
    *(float4*)(part + g * HD + 4 * c) = acc;
}
#define MV_REDUCE4(bias, j) ((bias)[j] + part[j] + part[HD + (j)] + part[2 * HD + (j)] + part[3 * HD + (j)])

__global__ __launch_bounds__(512) void g_kernel(
    const float* __restrict__ times, const float* __restrict__ W_noise,
    const float* __restrict__ b_noise, const float* __restrict__ Wg1,
    const float* __restrict__ bg1, const float* __restrict__ Wg2,
    const float* __restrict__ bg2, float* __restrict__ gs)
{
    int t = blockIdx.x;
    int j = threadIdx.x;
    __shared__ float tt[HD];
    __shared__ float h[HD];
    __shared__ float part[4 * HD];
    float tv = times[t];
    tt[j] = tv * W_noise[j] + b_noise[j];
    __syncthreads();
    mv_part<HD>(Wg1, tt, part, j);
    __syncthreads();
    h[j] = lipswish(MV_REDUCE4(bg1, j));
    __syncthreads();
    mv_part<HD>(Wg2, h, part, j);
    __syncthreads();
    float dt = times[t + 1] - times[t];
    gs[t * HD + j] = MV_REDUCE4(bg2, j) * sqrtf(dt);
}

// ---------------------------------------------------------------------------
// Pair-split fp16 matvec: block computes cols [h*256, h*256+256) for 2 rows.
// 512 threads = 16 k-groups (g=j>>5) x 32 col-octets (o=j&31).
// Each thread: 8 cols x 2 rows, one uint4 (8 halves) weight load per k,
// reused for both rows (16 fma / 16B load).
// part layout: [16 groups][2 rows][256 cols].
// ---------------------------------------------------------------------------
template<int K, int AST>
__device__ __forceinline__ void mv_pair_h(const __half* __restrict__ W,
                                          const float* act, int h, float* part, int j)
{
    const int g = j >> 5, o = j & 31;
    constexpr int kpg = K / 16;
    const int k0 = g * kpg;
    const int cb = h * 256 + (o << 3);
    float acc0[8], acc1[8];
#pragma unroll
    for (int i = 0; i < 8; ++i) { acc0[i] = 0.f; acc1[i] = 0.f; }
#pragma unroll 8
    for (int k = k0; k < k0 + kpg; ++k) {
        float x0 = act[k];
        float x1 = act[AST + k];
        uint4 raw = *(const uint4*)(W + ((size_t)k << 9) + cb);
        const __half2* hp = (const __half2*)&raw;
#pragma unroll
        for (int q = 0; q < 4; ++q) {
            float2 f = __half22float2(hp[q]);
            acc0[2*q]   = fmaf(x0, f.x, acc0[2*q]);
            acc0[2*q+1] = fmaf(x0, f.y, acc0[2*q+1]);
            acc1[2*q]   = fmaf(x1, f.x, acc1[2*q]);
            acc1[2*q+1] = fmaf(x1, f.y, acc1[2*q+1]);
        }
    }
    float* pb = part + (g << 9) + (o << 3);
    *(float4*)(pb)       = make_float4(acc0[0], acc0[1], acc0[2], acc0[3]);
    *(float4*)(pb + 4)   = make_float4(acc0[4], acc0[5], acc0[6], acc0[7]);
    *(float4*)(pb + 256) = make_float4(acc1[0], acc1[1], acc1[2], acc1[3]);
    *(float4*)(pb + 260) = make_float4(acc1[4], acc1[5], acc1[6], acc1[7]);
}

// fp32 variant for one-time W_init (K=64, row stride 512 floats)
__device__ __forceinline__ void mv_pair_f(const float* __restrict__ W,
                                          const float* act, int h, float* part, int j)
{
    const int g = j >> 5, o = j & 31;
    const int k0 = g * 4;
    const int cb = h * 256 + (o << 3);
    float acc0[8], acc1[8];
#pragma unroll
    for (int i = 0; i < 8; ++i) { acc0[i] = 0.f; acc1[i] = 0.f; }
#pragma unroll
    for (int k = k0; k < k0 + 4; ++k) {
        float x0 = act[k], x1 = act[64 + k];
        float4 wa = *(const float4*)(W + (size_t)k * HD + cb);
        float4 wb = *(const float4*)(W + (size_t)k * HD + cb + 4);
        acc0[0] = fmaf(x0, wa.x, acc0[0]); acc0[1] = fmaf(x0, wa.y, acc0[1]);
        acc0[2] = fmaf(x0, wa.z, acc0[2]); acc0[3] = fmaf(x0, wa.w, acc0[3]);
        acc0[4] = fmaf(x0, wb.x, acc0[4]); acc0[5] = fmaf(x0, wb.y, acc0[5]);
        acc0[6] = fmaf(x0, wb.z, acc0[6]); acc0[7] = fmaf(x0, wb.w, acc0[7]);
        acc1[0] = fmaf(x1, wa.x, acc1[0]); acc1[1] = fmaf(x1, wa.y, acc1[1]);
        acc1[2] = fmaf(x1, wa.z, acc1[2]); acc1[3] = fmaf(x1, wa.w, acc1[3]);
        acc1[4] = fmaf(x1, wb.x, acc1[4]); acc1[5] = fmaf(x1, wb.y, acc1[5]);
        acc1[6] = fmaf(x1, wb.z, acc1[6]); acc1[7] = fmaf(x1, wb.w, acc1[7]);
    }
    float* pb = part + (g << 9) + (o << 3);
    *(float4*)(pb)       = make_float4(acc0[0], acc0[1], acc0[2], acc0[3]);
    *(float4*)(pb + 4)   = make_float4(acc0[4], acc0[5], acc0[6], acc0[7]);
    *(float4*)(pb + 256) = make_float4(acc1[0], acc1[1], acc1[2], acc1[3]);
    *(float4*)(pb + 260) = make_float4(acc1[4], acc1[5], acc1[6], acc1[7]);
}

__device__ __forceinline__ float reduce16(const float* part, int j) {
    const int r = j >> 8, c = j & 255;
    const float* q = part + (r << 8) + c;
    float s0 = 0.f, s1 = 0.f, s2 = 0.f, s3 = 0.f;
#pragma unroll
    for (int g = 0; g < 16; g += 4) {
        s0 += q[(size_t)(g + 0) << 9]; s1 += q[(size_t)(g + 1) << 9];
        s2 += q[(size_t)(g + 2) << 9]; s3 += q[(size_t)(g + 3) << 9];
    }
    return (s0 + s1) + (s2 + s3);
}

// ---------------------------------------------------------------------------
// Pairwise sync: publish own flag (release), spin on partner (acquire).
// Both halves publish BEFORE waiting -> no deadlock. All 256 blocks are
// co-resident (grid == 256 == #CUs, 1 block/CU).
// ---------------------------------------------------------------------------
__device__ __forceinline__ void pair_sync(unsigned* flags, int p, int h,
                                          int eseq, int j)
{
    __syncthreads();
    if (j == 0) {
        __threadfence();
        __hip_atomic_fetch_add(&flags[p * 2 + h], 1u,
                               __ATOMIC_RELEASE, __HIP_MEMORY_SCOPE_AGENT);
        while (__hip_atomic_load(&flags[p * 2 + (1 - h)],
                                 __ATOMIC_ACQUIRE, __HIP_MEMORY_SCOPE_AGENT)
               < (unsigned)eseq)
            __builtin_amdgcn_s_sleep(2);
    }
    __syncthreads();
}

// exchange 512 values (1/thread): publish own half, receive partner half into LDS
__device__ __forceinline__ void exch512(float v, float* dst, int stride, int colofs,
                                        float* xb_own, float* xb_oth,
                                        unsigned* flags, int p, int h, int eseq, int j)
{
    const int r = j >> 8, c = j & 255;
    __hip_atomic_store(&xb_own[j], v, __ATOMIC_RELAXED, __HIP_MEMORY_SCOPE_AGENT);
    dst[r * stride + colofs + h * 256 + c] = v;
    pair_sync(flags, p, h, eseq, j);
    float pv = __hip_atomic_load(&xb_oth[j], __ATOMIC_RELAXED, __HIP_MEMORY_SCOPE_AGENT);
    dst[r * stride + colofs + (1 - h) * 256 + c] = pv;
    __syncthreads();
}

// y-update exchange with fused K-split decode: publishes y half + 128 decode
// partials; consumer sums partner partials -> full decode, zero extra syncs.
__device__ __forceinline__ void y_exchange_decode(
    float yn, int tidx, float* catA, float* part, float* dp,
    const __half* __restrict__ W_dec_h, const float* __restrict__ b_dec,
    float* xb_own, float* xb_oth, unsigned* flags, int p, int h, int eseq,
    int j, float* __restrict__ out)
{
    const int r = j >> 8, c = j & 255, col = h * 256 + c;
    __hip_atomic_store(&xb_own[j], yn, __ATOMIC_RELAXED, __HIP_MEMORY_SCOPE_AGENT);
    catA[r * 1024 + col] = yn;
    __syncthreads();
    // decode partial over LOCAL k half (just-computed local y cols)
    {
        const int g2 = j >> 7, q = j & 127, rr = q >> 6, dc = q & 63;
        const int kb = h * 256 + g2 * 64;
        const float* yv = catA + rr * 1024;
        float a = 0.f;
#pragma unroll 8
        for (int k = kb; k < kb + 64; ++k)
            a = fmaf(yv[k], __half2float(W_dec_h[((size_t)k << 6) + dc]), a);
        part[(g2 << 7) + q] = a;
    }
    __syncthreads();
    if (j < 128) {
        float s = part[j] + part[128 + j] + part[256 + j] + part[384 + j];
        dp[j] = s;
        __hip_atomic_store(&xb_own[512 + j], s, __ATOMIC_RELAXED, __HIP_MEMORY_SCOPE_AGENT);
    }
    pair_sync(flags, p, h, eseq, j);
    {
        float pv = __hip_atomic_load(&xb_oth[j], __ATOMIC_RELAXED, __HIP_MEMORY_SCOPE_AGENT);
        catA[r * 1024 + (1 - h) * 256 + c] = pv;
    }
    if (j < 128 && h == 0) {   // dp+o2 == o2+dp bit-exact, so one half stores
        const int rr = j >> 6, dc = j & 63;
        float o2 = __hip_atomic_load(&xb_oth[512 + j], __ATOMIC_RELAXED, __HIP_MEMORY_SCOPE_AGENT);
        out[((size_t)(2 * p + rr) * TT + tidx) * DOUT + dc] = dp[j] + o2 + b_dec[dc];
    }
    if (j < 128 && h == 1) {
        const int rr = j >> 6, dc = j & 63;
        float o2 = __hip_atomic_load(&xb_oth[512 + j], __ATOMIC_RELAXED, __HIP_MEMORY_SCOPE_AGENT);
        out[((size_t)(2 * p + rr) * TT + tidx) * DOUT + dc] = o2 + dp[j] + b_dec[dc];
    }
    __syncthreads();
}

// ---------------------------------------------------------------------------
// Pair-split SDE scan: 256 blocks; block (p,h): rows {2p,2p+1}, cols half h.
// ---------------------------------------------------------------------------
__global__ __launch_bounds__(512) void scan_kernel(
    const float* __restrict__ coeffs,
    const float* __restrict__ times,
    const float* __restrict__ noise,
    const float* __restrict__ b_X,
    const float* __restrict__ b_emb,
    const float* __restrict__ bf1,
    const float* __restrict__ bf2,
    const float* __restrict__ b_out,
    const float* __restrict__ W_init, const float* __restrict__ b_init,
    const float* __restrict__ b_dec,
    const float* __restrict__ W_cls, const float* __restrict__ b_cls,
    const int* __restrict__ mask,
    const float* __restrict__ gs,
    const __half* __restrict__ Wh,
    float* __restrict__ xbuf,
    unsigned* __restrict__ flags,
    float* __restrict__ out)
{
    const int bid = blockIdx.x;
    const int h = bid >> 7, p = bid & 127;
    const int j = threadIdx.x;
    const int r = j >> 8, c = j & 255, col = h * 256 + c;
    int eseq = 0;

    const __half* __restrict__ W_X_h   = Wh + OFF_WX;
    const __half* __restrict__ W_emb_h = Wh + OFF_WEMB;
    const __half* __restrict__ Wf1_h   = Wh + OFF_WF1;
    const __half* __restrict__ Wf2_h   = Wh + OFF_WF2;
    const __half* __restrict__ W_out_h = Wh + OFF_WOUT;
    const __half* __restrict__ W_dec_h = Wh + OFF_WDEC;

    __shared__ float catA[2 * 1024];   // per row: [y(512) | xw(512)]
    __shared__ float actA[2 * HD];
    __shared__ float actB[2 * HD];
    __shared__ float part[16 * HD];    // 32 KB partials
    __shared__ float avec[2 * DIN];
    __shared__ float zfin[2 * HD];
    __shared__ float dp[128];
    __shared__ float tl[TT];
    __shared__ int   li[2];

#define XBPTRS \
    float* xb = xbuf + ((size_t)(eseq & 1) * NPAIR + p) * (2 * XSLOT); \
    float* xb_own = xb + h * XSLOT;                                     \
    float* xb_oth = xb + (1 - h) * XSLOT;

    if (j < TT) tl[j] = times[j];

    // per-row last_idx from mask (rows 2p, 2p+1)
    {
        int rr = j >> 8, q = j & 255;
        part[j] = (q < TT) ? (float)mask[(2 * p + rr) * TT + q] : 0.f;
        __syncthreads();
        for (int s = 128; s > 0; s >>= 1) {
            if ((j & 255) < s) part[j] += part[j + s];
            __syncthreads();
        }
        if (j < 2) li[j] = (int)part[j << 8] - 1;
        __syncthreads();
    }

    // ---- y0 = a0 @ W_init + b_init (fp32), exchange + decode idx 0 ----
    if (j < 32) {
        int rr = j >> 4, q = j & 15;
        ((float4*)avec)[j] =
            ((const float4*)coeffs)[((size_t)(2 * p + rr) * (TT - 1) + 0) * 64 + q];
    }
    __syncthreads();
    mv_pair_f(W_init, avec, h, part, j);
    __syncthreads();
    {
        float y0 = b_init[col] + reduce16(part, j);
        ++eseq; XBPTRS;
        y_exchange_decode(y0, 0, catA, part, dp, W_dec_h, b_dec,
                          xb_own, xb_oth, flags, p, h, eseq, j, out);
    }
    if (li[0] == 0) zfin[j] = catA[j];
    if (li[1] == 0) zfin[512 + j] = catA[1024 + j];

    // ---- main scan ----
    for (int t = 0; t < TT - 1; ++t) {
        if (j < 32) {
            int rr = j >> 4, q = j & 15;
            ((float4*)avec)[j] =
                ((const float4*)coeffs)[((size_t)(2 * p + rr) * (TT - 1) + t) * 64 + q];
        }
        __syncthreads();
        // xw = a_t @ W_X + b_X  -> catA[:,512+...]
        mv_pair_h<DIN, DIN>(W_X_h, avec, h, part, j);
        __syncthreads();
        {
            float v = b_X[col] + reduce16(part, j);
            ++eseq; XBPTRS;
            exch512(v, catA, 1024, 512, xb_own, xb_oth, flags, p, h, eseq, j);
        }
        // z1 = [y,xw] @ W_emb + b_emb -> actA
        mv_pair_h<1024, 1024>(W_emb_h, catA, h, part, j);
        __syncthreads();
        {
            float v = b_emb[col] + reduce16(part, j);
            ++eseq; XBPTRS;
            exch512(v, actA, HD, 0, xb_own, xb_oth, flags, p, h, eseq, j);
        }
        // z2 = lipswish(z1 @ Wf1 + bf1) -> actB
        mv_pair_h<HD, HD>(Wf1_h, actA, h, part, j);
        __syncthreads();
        {
            float v = lipswish(bf1[col] + reduce16(part, j));
            ++eseq; XBPTRS;
            exch512(v, actB, HD, 0, xb_own, xb_oth, flags, p, h, eseq, j);
        }
        // z3 = z2 @ Wf2 + bf2 -> actA
        mv_pair_h<HD, HD>(Wf2_h, actB, h, part, j);
        __syncthreads();
        {
            float v = bf2[col] + reduce16(part, j);
            ++eseq; XBPTRS;
            exch512(v, actA, HD, 0, xb_own, xb_oth, flags, p, h, eseq, j);
        }
        // drift; Euler update; y exchange + fused decode
        mv_pair_h<HD, HD>(W_out_h, actA, h, part, j);
        __syncthreads();
        {
            float dr = b_out[col] + reduce16(part, j);
            float dtv = tl[t + 1] - tl[t];
            const int row = 2 * p + r;
            float yn = catA[r * 1024 + col] + dr * dtv
                     + gs[(size_t)t * HD + col] * noise[((size_t)t * BB + row) * HD + col];
            ++eseq; XBPTRS;
            y_exchange_decode(yn, t + 1, catA, part, dp, W_dec_h, b_dec,
                              xb_own, xb_oth, flags, p, h, eseq, j, out);
        }
        if (t + 1 == li[0]) zfin[j] = catA[j];
        if (t + 1 == li[1]) zfin[512 + j] = catA[1024 + j];
    }

    // ---- logits: block (p,h) handles row 2p+h ----
    __syncthreads();
    {
        const int cc = j & 15, seg = j >> 4;
        float pr = 0.f;
        if (cc < NCLS) {
            const float* z = zfin + h * HD;
#pragma unroll
            for (int k = seg * 16; k < seg * 16 + 16; ++k)
                pr = fmaf(z[k], W_cls[k * NCLS + cc], pr);
        }
        part[j] = pr;
        __syncthreads();
        if (j < NCLS) {
            float s = b_cls[j];
#pragma unroll
            for (int sg = 0; sg < 32; ++sg) s += part[sg * 16 + j];
            out[(size_t)BB * TT * DOUT + (2 * p + h) * NCLS + j] = s;
        }
    }
#undef XBPTRS
}

extern "C" void kernel_launch(void* const* d_in, const int* in_sizes, int n_in,
                              void* d_out, int out_size, void* d_ws, size_t ws_size,
                              hipStream_t stream)
{
    const float* coeffs  = (const float*)d_in[0];
    const float* times   = (const float*)d_in[1];
    const float* noise   = (const float*)d_in[2];
    const float* W_X     = (const float*)d_in[3];
    const float* b_X     = (const float*)d_in[4];
    const float* W_emb   = (const float*)d_in[5];
    const float* b_emb   = (const float*)d_in[6];
    const float* Wf1     = (const float*)d_in[7];
    const float* bf1     = (const float*)d_in[8];
    const float* Wf2     = (const float*)d_in[9];
    const float* bf2     = (const float*)d_in[10];
    const float* W_out   = (const float*)d_in[11];
    const float* b_out   = (const float*)d_in[12];
    const float* W_noise = (const float*)d_in[13];
    const float* b_noise = (const float*)d_in[14];
    const float* Wg1     = (const float*)d_in[15];
    const float* bg1     = (const float*)d_in[16];
    const float* Wg2     = (const float*)d_in[17];
    const float* bg2     = (const float*)d_in[18];
    const float* W_init  = (const float*)d_in[19];
    const float* b_init  = (const float*)d_in[20];
    const float* W_dec   = (const float*)d_in[21];
    const float* b_dec   = (const float*)d_in[22];
    const float* W_cls   = (const float*)d_in[23];
    const float* b_cls   = (const float*)d_in[24];
    const int*   mask    = (const int*)d_in[25];

    float*    gs    = (float*)d_ws;
    __half*   Wh    = (__half*)((char*)d_ws + GS_BYTES);
    float*    xbuf  = (float*)((char*)d_ws + XBUF_OFF);
    unsigned* flags = (unsigned*)((char*)d_ws + FLAG_OFF);
    float*    out   = (float*)d_out;

    hipMemsetAsync(flags, 0, 2 * NPAIR * sizeof(unsigned), stream);

    cvt_kernel<<<dim3(NHALVES / 512), dim3(512), 0, stream>>>(
        W_X, W_emb, Wf1, Wf2, W_out, W_dec, Wh);

    g_kernel<<<dim3(TT - 1), dim3(HD), 0, stream>>>(
        times, W_noise, b_noise, Wg1, bg1, Wg2, bg2, gs);

    scan_kernel<<<dim3(2 * NPAIR), dim3(HD), 0, stream>>>(
        coeffs, times, noise, b_X, b_emb, bf1, bf2, b_out,
        W_init, b_init, b_dec, W_cls, b_cls, mask, gs, Wh, xbuf, flags, out);
}

// Round 5
// 5133.113 us; speedup vs baseline: 2.6002x; 2.6002x over previous
//
#include <hip/hip_runtime.h>
#include <hip/hip_fp16.h>
#include <math.h>

#define HD   512
#define BB   256
#define TT   200
#define DIN  64
#define DOUT 64
#define NCLS 10
#define LIPC 0.909f

// d_ws layout: gs (fp32, (TT-1)*HD) then pair-packed half2 weights.
// W2[kp][col] = (W[2kp][col], W[2kp+1][col]) as one uint (half2).
#define GS_BYTES    407552
#define OFF2_WX     0              // 32 kp x 512
#define OFF2_WEMB   16384          // 512 kp x 512
#define OFF2_WF1    278528         // 256 kp x 512
#define OFF2_WF2    409600
#define OFF2_WOUT   540672
#define OFF2_WDEC   671744         // 256 kp x 64
#define NPACK       688128         // total uints

__device__ __forceinline__ float lipswish(float x) {
    return LIPC * x / (1.0f + expf(-x));
}

typedef _Float16 h2_t __attribute__((ext_vector_type(2)));

__device__ __forceinline__ float fdot2u(unsigned a, unsigned b, float c) {
    return __builtin_amdgcn_fdot2(__builtin_bit_cast(h2_t, a),
                                  __builtin_bit_cast(h2_t, b), c, false);
}

// pack adjacent-column fp32 activations into half2 LDS once per layer:
// thread j holds v for col j; even lanes write pair (j, j+1).
__device__ __forceinline__ void pack_store(float v, unsigned* dstH, int j) {
    float other = __shfl_xor(v, 1, 64);
    if ((j & 1) == 0) {
        __half2 hp = __floats2half2_rn(v, other);
        dstH[j >> 1] = __builtin_bit_cast(unsigned, hp);
    }
}

// ---------------------------------------------------------------------------
// cvt: fp32 weights -> pair-packed half2. 1344 blocks x 512.
// ---------------------------------------------------------------------------
__global__ __launch_bounds__(512) void cvt_kernel(
    const float* __restrict__ W_X,  const float* __restrict__ W_emb,
    const float* __restrict__ Wf1,  const float* __restrict__ Wf2,
    const float* __restrict__ W_out, const float* __restrict__ W_dec,
    unsigned* __restrict__ dst)
{
    int bid = blockIdx.x;
    size_t e = ((size_t)bid << 9) + threadIdx.x;
    const float* src; size_t off2; int csh;
    if      (bid < 32)   { src = W_X;   off2 = OFF2_WX;   csh = 9; }
    else if (bid < 544)  { src = W_emb; off2 = OFF2_WEMB; csh = 9; }
    else if (bid < 800)  { src = Wf1;   off2 = OFF2_WF1;  csh = 9; }
    else if (bid < 1056) { src = Wf2;   off2 = OFF2_WF2;  csh = 9; }
    else if (bid < 1312) { src = W_out; off2 = OFF2_WOUT; csh = 9; }
    else                 { src = W_dec; off2 = OFF2_WDEC; csh = 6; }
    size_t e2 = e - off2;
    size_t kp = e2 >> csh;
    size_t c  = e2 & (((size_t)1 << csh) - 1);
    size_t C  = (size_t)1 << csh;
    __half2 hp = __floats2half2_rn(src[(2 * kp) * C + c], src[(2 * kp + 1) * C + c]);
    dst[e] = __builtin_bit_cast(unsigned, hp);
}

// ---------------------------------------------------------------------------
// fp32 partial matvec (g_kernel + one-time W_init): 4 k-groups x 128 f4-cols
// ---------------------------------------------------------------------------
template<int K>
__device__ __forceinline__ void mv_part(const float* __restrict__ W,
                                        const float* src, float* part, int j)
{
    const int g = j >> 7, c = j & 127;
    const int kpg = K >> 2;
    const int k0 = g * kpg;
    const float4* __restrict__ W4 = (const float4*)W;
    float4 acc; acc.x = acc.y = acc.z = acc.w = 0.f;
#pragma unroll 2
    for (int k = k0; k < k0 + kpg; k += 4) {
        float4 a  = *(const float4*)(src + k);
        float4 w0 = W4[(size_t)(k + 0) * 128 + c];
        float4 w1 = W4[(size_t)(k + 1) * 128 + c];
        float4 w2 = W4[(size_t)(k + 2) * 128 + c];
        float4 w3 = W4[(size_t)(k + 3) * 128 + c];
        acc.x = fmaf(a.x, w0.x, acc.x); acc.y = fmaf(a.x, w0.y, acc.y);
        acc.z = fmaf(a.x, w0.z, acc.z); acc.w = fmaf(a.x, w0.w, acc.w);
        acc.x = fmaf(a.y, w1.x, acc.x); acc.y = fmaf(a.y, w1.y, acc.y);
        acc.z = fmaf(a.y, w1.z, acc.z); acc.w = fmaf(a.y, w1.w, acc.w);
        acc.x = fmaf(a.z, w2.x, acc.x); acc.y = fmaf(a.z, w2.y, acc.y);
        acc.z = fmaf(a.z, w2.z, acc.z); acc.w = fmaf(a.z, w2.w, acc.w);
        acc.x = fmaf(a.w, w3.x, acc.x); acc.y = fmaf(a.w, w3.y, acc.y);
        acc.z = fmaf(a.w, w3.z, acc.z); acc.w = fmaf(a.w, w3.w, acc.w);
    }
    *(float4*)(part + g * HD + 4 * c) = acc;
}
#define MV_REDUCE4(bias, j) ((bias)[j] + part[j] + part[HD + (j)] + part[2 * HD + (j)] + part[3 * HD + (j)])
#define MV_REDUCE8(bias, j) ((bias)[j] + ((part[j] + part[HD + (j)]) + (part[2 * HD + (j)] + part[3 * HD + (j)])) \
                           + ((part[4 * HD + (j)] + part[5 * HD + (j)]) + (part[6 * HD + (j)] + part[7 * HD + (j)])))

__global__ __launch_bounds__(512) void g_kernel(
    const float* __restrict__ times, const float* __restrict__ W_noise,
    const float* __restrict__ b_noise, const float* __restrict__ Wg1,
    const float* __restrict__ bg1, const float* __restrict__ Wg2,
    const float* __restrict__ bg2, float* __restrict__ gs)
{
    int t = blockIdx.x;
    int j = threadIdx.x;
    __shared__ float tt[HD];
    __shared__ float h[HD];
    __shared__ float part[4 * HD];
    float tv = times[t];
    tt[j] = tv * W_noise[j] + b_noise[j];
    __syncthreads();
    mv_part<HD>(Wg1, tt, part, j);
    __syncthreads();
    h[j] = lipswish(MV_REDUCE4(bg1, j));
    __syncthreads();
    mv_part<HD>(Wg2, h, part, j);
    __syncthreads();
    float dt = times[t + 1] - times[t];
    gs[t * HD + j] = MV_REDUCE4(bg2, j) * sqrtf(dt);
}

// ---------------------------------------------------------------------------
// dot2 matvec, 512 output cols: 8 kp-groups (g=j>>6) x 64 col-octets.
// Per kp: 1 ds_read_b32 (act half2 broadcast) + 2 dwordx4 (8 half2 weights)
// + 8 v_dot2_f32_f16 => 16 MACs.
// ---------------------------------------------------------------------------
template<int KP>
__device__ __forceinline__ void mv_dot2(const unsigned* __restrict__ W2,
                                        const unsigned* actH, float* part, int j)
{
    const int g = j >> 6, o8 = (j & 63) << 3;
    constexpr int kpg = KP / 8;
    const int kp0 = g * kpg;
    float acc[8];
#pragma unroll
    for (int i = 0; i < 8; ++i) acc[i] = 0.f;
#pragma unroll 8
    for (int kp = kp0; kp < kp0 + kpg; ++kp) {
        unsigned ap = actH[kp];
        uint4 w0 = *(const uint4*)(W2 + ((size_t)kp << 9) + o8);
        uint4 w1 = *(const uint4*)(W2 + ((size_t)kp << 9) + o8 + 4);
        acc[0] = fdot2u(ap, w0.x, acc[0]);
        acc[1] = fdot2u(ap, w0.y, acc[1]);
        acc[2] = fdot2u(ap, w0.z, acc[2]);
        acc[3] = fdot2u(ap, w0.w, acc[3]);
        acc[4] = fdot2u(ap, w1.x, acc[4]);
        acc[5] = fdot2u(ap, w1.y, acc[5]);
        acc[6] = fdot2u(ap, w1.z, acc[6]);
        acc[7] = fdot2u(ap, w1.w, acc[7]);
    }
    float* pb = part + (g << 9) + o8;
    *(float4*)(pb)     = make_float4(acc[0], acc[1], acc[2], acc[3]);
    *(float4*)(pb + 4) = make_float4(acc[4], acc[5], acc[6], acc[7]);
}

// ---------------------------------------------------------------------------
// dot2 decode (512 -> 64) + store: 64 kp-groups (4 kp each) x 8 col-octets.
// ---------------------------------------------------------------------------
__device__ __forceinline__ void decode_store_d2(const unsigned* __restrict__ Wd2,
    const float* __restrict__ b_dec, const unsigned* yH, float* part, float* dscr,
    int j, float* __restrict__ outp)
{
    const int g = j >> 3, o8 = (j & 7) << 3;
    const int kp0 = g << 2;
    float acc[8];
#pragma unroll
    for (int i = 0; i < 8; ++i) acc[i] = 0.f;
#pragma unroll
    for (int kp = kp0; kp < kp0 + 4; ++kp) {
        unsigned ap = yH[kp];
        uint4 w0 = *(const uint4*)(Wd2 + ((size_t)kp << 6) + o8);
        uint4 w1 = *(const uint4*)(Wd2 + ((size_t)kp << 6) + o8 + 4);
        acc[0] = fdot2u(ap, w0.x, acc[0]);
        acc[1] = fdot2u(ap, w0.y, acc[1]);
        acc[2] = fdot2u(ap, w0.z, acc[2]);
        acc[3] = fdot2u(ap, w0.w, acc[3]);
        acc[4] = fdot2u(ap, w1.x, acc[4]);
        acc[5] = fdot2u(ap, w1.y, acc[5]);
        acc[6] = fdot2u(ap, w1.z, acc[6]);
        acc[7] = fdot2u(ap, w1.w, acc[7]);
    }
    float* pb = part + (g << 6) + o8;
    *(float4*)(pb)     = make_float4(acc[0], acc[1], acc[2], acc[3]);
    *(float4*)(pb + 4) = make_float4(acc[4], acc[5], acc[6], acc[7]);
    __syncthreads();
    {
        int o2 = j >> 6, col = j & 63;
        float s = 0.f;
#pragma unroll
        for (int i = 0; i < 8; ++i) s += part[((o2 << 3) + i) * 64 + col];
        dscr[(o2 << 6) + col] = s;
    }
    __syncthreads();
    if (j < DOUT) {
        float s = b_dec[j];
#pragma unroll
        for (int i = 0; i < 8; ++i) s += dscr[(i << 6) + j];
        outp[j] = s;
    }
}

// ---------------------------------------------------------------------------
// Batch-parallel SDE scan (round-3 structure), dot2 inner loops.
// grid = B blocks x 512 threads, one block per batch row.
// ---------------------------------------------------------------------------
__global__ __launch_bounds__(512) void scan_kernel(
    const float* __restrict__ coeffs,
    const float* __restrict__ times,
    const float* __restrict__ noise,
    const float* __restrict__ b_X,
    const float* __restrict__ b_emb,
    const float* __restrict__ bf1,
    const float* __restrict__ bf2,
    const float* __restrict__ b_out,
    const float* __restrict__ W_init, const float* __restrict__ b_init,
    const float* __restrict__ b_dec,
    const float* __restrict__ W_cls, const float* __restrict__ b_cls,
    const int* __restrict__ mask,
    const float* __restrict__ gs,
    const unsigned* __restrict__ W2,    // pair-packed half2 weights
    float* __restrict__ out)
{
    const int b = blockIdx.x;
    const int j = threadIdx.x;

    const unsigned* __restrict__ W_X_2   = W2 + OFF2_WX;
    const unsigned* __restrict__ W_emb_2 = W2 + OFF2_WEMB;
    const unsigned* __restrict__ Wf1_2   = W2 + OFF2_WF1;
    const unsigned* __restrict__ Wf2_2   = W2 + OFF2_WF2;
    const unsigned* __restrict__ W_out_2 = W2 + OFF2_WOUT;
    const unsigned* __restrict__ W_dec_2 = W2 + OFF2_WDEC;

    __shared__ float    yF[HD];          // fp32 y (Euler state)
    __shared__ unsigned catH[HD];        // [y pairs (256) | xw pairs (256)]
    __shared__ unsigned actAH[HD / 2];
    __shared__ unsigned actBH[HD / 2];
    __shared__ unsigned avecH[DIN / 2];
    __shared__ float    part[8 * HD];    // 16 KB partials
    __shared__ float    dscr[HD];
    __shared__ float    avec[DIN];
    __shared__ float    zfin[HD];
    __shared__ float    tl[TT];
    __shared__ int      last_idx_s;

    if (j < TT) tl[j] = times[j];

    // ---- per-row length from mask ----
    {
        int m = 0;
        for (int t = j; t < TT; t += 512) m += mask[b * TT + t];
        part[j] = (float)m;
        __syncthreads();
        for (int s = 256; s > 0; s >>= 1) {
            if (j < s) part[j] += part[j + s];
            __syncthreads();
        }
        if (j == 0) last_idx_s = (int)part[0] - 1;
        __syncthreads();
    }
    const int last_idx = last_idx_s;

    // ---- y0 = a0 @ W_init + b_init (fp32, one-time) ----
    if (j < DIN / 4)
        ((float4*)avec)[j] = ((const float4*)(coeffs + (size_t)b * (TT - 1) * 4 * DIN))[j];
    __syncthreads();
    mv_part<DIN>(W_init, avec, part, j);
    __syncthreads();
    {
        float y = MV_REDUCE4(b_init, j);
        yF[j] = y;
        pack_store(y, catH, j);
        if (last_idx == 0) zfin[j] = y;
    }
    __syncthreads();

    // ---- decode y0 ----
    decode_store_d2(W_dec_2, b_dec, catH, part, dscr, j,
                    out + ((size_t)b * TT + 0) * DOUT);

    // ---- main scan ----
    for (int t = 0; t < TT - 1; ++t) {
        // a_t (first 64 of the 256-wide coeff row), packed to half2
        if (j < DIN / 2) {
            float2 a2 = ((const float2*)(coeffs + ((size_t)b * (TT - 1) + t) * 4 * DIN))[j];
            __half2 hp = __floats2half2_rn(a2.x, a2.y);
            avecH[j] = __builtin_bit_cast(unsigned, hp);
        }
        __syncthreads();   // also closes decode's dscr phase
        // xw = a_t @ W_X + b_X  -> catH[256..]
        mv_dot2<DIN / 2>(W_X_2, avecH, part, j);
        __syncthreads();
        pack_store(MV_REDUCE8(b_X, j), catH + 256, j);
        __syncthreads();
        // z1 = [y,xw] @ W_emb + b_emb -> actAH
        mv_dot2<HD>(W_emb_2, catH, part, j);
        __syncthreads();
        pack_store(MV_REDUCE8(b_emb, j), actAH, j);
        __syncthreads();
        // z2 = lipswish(z1 @ Wf1 + bf1) -> actBH
        mv_dot2<HD / 2>(Wf1_2, actAH, part, j);
        __syncthreads();
        pack_store(lipswish(MV_REDUCE8(bf1, j)), actBH, j);
        __syncthreads();
        // z3 = z2 @ Wf2 + bf2 -> actAH
        mv_dot2<HD / 2>(Wf2_2, actBH, part, j);
        __syncthreads();
        pack_store(MV_REDUCE8(bf2, j), actAH, j);
        __syncthreads();
        // drift = z3 @ W_out + b_out; Euler update -> yF, catH[0..255]
        mv_dot2<HD / 2>(W_out_2, actAH, part, j);
        __syncthreads();
        {
            float dr = MV_REDUCE8(b_out, j);
            float dtv = tl[t + 1] - tl[t];
            float yn = yF[j] + dr * dtv
                     + gs[(size_t)t * HD + j] * noise[((size_t)t * BB + b) * HD + j];
            yF[j] = yn;
            pack_store(yn, catH, j);
            if (t + 1 == last_idx) zfin[j] = yn;
        }
        __syncthreads();
        // decode y_{t+1}
        decode_store_d2(W_dec_2, b_dec, catH, part, dscr, j,
                        out + ((size_t)b * TT + (t + 1)) * DOUT);
    }
    __syncthreads();

    // ---- logits (fp32, one-time) ----
    {
        int c = j & 15, seg = j >> 4;
        float p = 0.f;
        if (c < NCLS) {
#pragma unroll
            for (int k = seg * 16; k < seg * 16 + 16; ++k)
                p = fmaf(zfin[k], W_cls[k * NCLS + c], p);
        }
        part[j] = p;
        __syncthreads();
        if (j < NCLS) {
            float s = b_cls[j];
#pragma unroll
            for (int sg = 0; sg < 32; ++sg) s += part[sg * 16 + j];
            out[(size_t)BB * TT * DOUT + b * NCLS + j] = s;
        }
    }
}

extern "C" void kernel_launch(void* const* d_in, const int* in_sizes, int n_in,
                              void* d_out, int out_size, void* d_ws, size_t ws_size,
                              hipStream_t stream)
{
    const float* coeffs  = (const float*)d_in[0];
    const float* times   = (const float*)d_in[1];
    const float* noise   = (const float*)d_in[2];
    const float* W_X     = (const float*)d_in[3];
    const float* b_X     = (const float*)d_in[4];
    const float* W_emb   = (const float*)d_in[5];
    const float* b_emb   = (const float*)d_in[6];
    const float* Wf1     = (const float*)d_in[7];
    const float* bf1     = (const float*)d_in[8];
    const float* Wf2     = (const float*)d_in[9];
    const float* bf2     = (const float*)d_in[10];
    const float* W_out   = (const float*)d_in[11];
    const float* b_out   = (const float*)d_in[12];
    const float* W_noise = (const float*)d_in[13];
    const float* b_noise = (const float*)d_in[14];
    const float* Wg1     = (const float*)d_in[15];
    const float* bg1     = (const float*)d_in[16];
    const float* Wg2     = (const float*)d_in[17];
    const float* bg2     = (const float*)d_in[18];
    const float* W_init  = (const float*)d_in[19];
    const float* b_init  = (const float*)d_in[20];
    const float* W_dec   = (const float*)d_in[21];
    const float* b_dec   = (const float*)d_in[22];
    const float* W_cls   = (const float*)d_in[23];
    const float* b_cls   = (const float*)d_in[24];
    const int*   mask    = (const int*)d_in[25];

    float*    gs = (float*)d_ws;
    unsigned* W2 = (unsigned*)((char*)d_ws + GS_BYTES);
    float*   out = (float*)d_out;

    cvt_kernel<<<dim3(NPACK / 512), dim3(512), 0, stream>>>(
        W_X, W_emb, Wf1, Wf2, W_out, W_dec, W2);

    g_kernel<<<dim3(TT - 1), dim3(HD), 0, stream>>>(
        times, W_noise, b_noise, Wg1, bg1, Wg2, bg2, gs);

    scan_kernel<<<dim3(BB), dim3(HD), 0, stream>>>(
        coeffs, times, noise, b_X, b_emb, bf1, bf2, b_out,
        W_init, b_init, b_dec, W_cls, b_cls, mask, gs, W2, out);
}